// Round 1
// baseline (338.066 us; speedup 1.0000x reference)
//
#include <hip/hip_runtime.h>

// LIF scan: mem = 0.25*mem + x[t]; spk = (mem >= 1); mem -= spk.
// x: [T=100, 32, 16384] f32. Parallel over N=524288 neurons, sequential in T.
// Memory-bound: 420 MB total traffic, floor ~67us @ 6.3 TB/s.

constexpr int T = 100;
constexpr int N = 32 * 16384;      // 524288 neurons
constexpr int NV4 = N / 4;         // 131072 float4 columns

__global__ __launch_bounds__(256) void lif_kernel(const float4* __restrict__ x,
                                                  float4* __restrict__ out) {
    const int i = blockIdx.x * 256 + threadIdx.x;   // float4 column index
    const float4* xp = x + i;
    float4* op = out + i;

    float4 mem = make_float4(0.f, 0.f, 0.f, 0.f);

    // Unroll so 4 independent 16B loads are in flight (x[t+1] doesn't depend on mem).
#pragma unroll 4
    for (int t = 0; t < T; ++t) {
        const float4 xt = xp[(size_t)t * NV4];
        float4 s;
        // __fmul_rn/__fadd_rn: match numpy's separate mul+add exactly (no FMA
        // contraction) — hard threshold at 1.0 makes ulp drift cascade.
        mem.x = __fadd_rn(__fmul_rn(0.25f, mem.x), xt.x);
        mem.y = __fadd_rn(__fmul_rn(0.25f, mem.y), xt.y);
        mem.z = __fadd_rn(__fmul_rn(0.25f, mem.z), xt.z);
        mem.w = __fadd_rn(__fmul_rn(0.25f, mem.w), xt.w);
        s.x = (mem.x >= 1.0f) ? 1.0f : 0.0f;
        s.y = (mem.y >= 1.0f) ? 1.0f : 0.0f;
        s.z = (mem.z >= 1.0f) ? 1.0f : 0.0f;
        s.w = (mem.w >= 1.0f) ? 1.0f : 0.0f;
        mem.x -= s.x;
        mem.y -= s.y;
        mem.z -= s.z;
        mem.w -= s.w;
        op[(size_t)t * NV4] = s;
    }
}

extern "C" void kernel_launch(void* const* d_in, const int* in_sizes, int n_in,
                              void* d_out, int out_size, void* d_ws, size_t ws_size,
                              hipStream_t stream) {
    const float4* x = (const float4*)d_in[0];
    float4* out = (float4*)d_out;
    const int blocks = NV4 / 256;   // 512
    lif_kernel<<<blocks, 256, 0, stream>>>(x, out);
}

// Round 3
// 333.924 us; speedup vs baseline: 1.0124x; 1.0124x over previous
//
#include <hip/hip_runtime.h>

// LIF scan: mem = 0.25*mem + x[t]; spk = (mem >= 1); mem -= spk.
// x: [T=100, 32, 16384] f32. Parallel over N=524288 neurons, sequential in T.
// Memory-bound: 420 MB kernel traffic, floor ~67us @ 6.3 TB/s.
//
// R3: float2/thread -> 1024 blocks (16 waves/CU, 2x R1 TLP); T chunked by 10
// with a statically-indexed register window (10 independent loads in flight,
// 2.5x R1 MLP). R2's rotating buf[t%PF] + full T-unroll core-dumped the
// harness — keep register windows statically indexed inside #pragma unroll.

constexpr int T = 100;
constexpr int N = 32 * 16384;      // 524288 neurons
constexpr int NV2 = N / 2;         // 262144 float2 columns
constexpr int CH = 10;             // chunk: 10 loads in flight, T = 10 chunks

__global__ __launch_bounds__(256) void lif_kernel(const float2* __restrict__ x,
                                                  float2* __restrict__ out) {
    const int i = blockIdx.x * 256 + threadIdx.x;   // float2 column index
    const float2* xp = x + i;
    float2* op = out + i;

    float2 mem = make_float2(0.f, 0.f);

    for (int c = 0; c < T; c += CH) {              // 10 chunks, not unrolled
        float2 xs[CH];
#pragma unroll
        for (int k = 0; k < CH; ++k)               // 10 independent loads
            xs[k] = xp[(size_t)(c + k) * NV2];

#pragma unroll
        for (int k = 0; k < CH; ++k) {
            const float2 xt = xs[k];
            float2 s;
            // __fmul_rn/__fadd_rn: match numpy's separate mul+add bit-exactly
            // (no FMA contraction) — hard threshold makes ulp drift cascade.
            mem.x = __fadd_rn(__fmul_rn(0.25f, mem.x), xt.x);
            mem.y = __fadd_rn(__fmul_rn(0.25f, mem.y), xt.y);
            s.x = (mem.x >= 1.0f) ? 1.0f : 0.0f;
            s.y = (mem.y >= 1.0f) ? 1.0f : 0.0f;
            mem.x -= s.x;
            mem.y -= s.y;
            op[(size_t)(c + k) * NV2] = s;
        }
    }
}

extern "C" void kernel_launch(void* const* d_in, const int* in_sizes, int n_in,
                              void* d_out, int out_size, void* d_ws, size_t ws_size,
                              hipStream_t stream) {
    const float2* x = (const float2*)d_in[0];
    float2* out = (float2*)d_out;
    const int blocks = NV2 / 256;   // 1024 -> 4 blocks/CU, 16 waves/CU
    lif_kernel<<<blocks, 256, 0, stream>>>(x, out);
}